// Round 9
// baseline (323.604 us; speedup 1.0000x reference)
//
#include <hip/hip_runtime.h>

// GCN: 100K nodes, 3.2M edges, 128 -> 16 -> 16 -> 16 -> 2, mean-pool to 64 graphs.
// R9 vs R8:
//  (1) k_build / k_bsort: single LDS-atomic pass (rank-during-count + scan),
//      halving the 6.4M-atomic cost that bound k_build (45us, VALU 5.8%).
//  (2) agg kernels: 4 threads/node, uint2 (8B) gathers, x4 unroll (32B in flight).
//  (3) k_pool fused into k_agg2 epilogue.
// h stored bf16-packed (L2-resident); MFMA k_t0; dtype-adaptive IO.

#define NN 100000
#define NE 3200000
#define NF 128
#define NH 16
#define NO 2
#define NG 64
#define NBLK 391        // ceil(NN/256)
#define BN 256          // nodes per bucket
#define NBUK 391        // ceil(NN/BN)
#define CHUNK 4096
#define NBLKA 782       // ceil(NE/CHUNK)
#define CAPF 10240      // bucket region capacity (mean 8184, sigma ~90)
#define NT0 6250        // 16-node tiles

typedef __attribute__((ext_vector_type(8))) short short8;
typedef __attribute__((ext_vector_type(4))) float float4v;

// ---------------- dtype-dispatched IO helpers ----------------

__device__ __forceinline__ float ldf(const void* p, int i, int f32) {
  if (f32) return ((const float*)p)[i];
  unsigned int u = ((const unsigned short*)p)[i];
  return __uint_as_float(u << 16);
}
__device__ __forceinline__ int ldi(const void* p, int i, int i64) {
  if (i64) return (int)((const long long*)p)[i];
  return ((const int*)p)[i];
}
__device__ __forceinline__ void stf(void* p, int i, float v, int f32) {
  if (f32) {
    ((float*)p)[i] = v;
  } else {
    unsigned int w = __float_as_uint(v);
    unsigned int r = (w + 0x7fffu + ((w >> 16) & 1u)) >> 16;
    ((unsigned short*)p)[i] = (unsigned short)r;
  }
}
__device__ __forceinline__ float bf16lo(unsigned int u) { return __uint_as_float(u << 16); }
__device__ __forceinline__ float bf16hi(unsigned int u) { return __uint_as_float(u & 0xffff0000u); }
__device__ __forceinline__ unsigned int packbf(float x, float y) {
  unsigned int a = __float_as_uint(x);
  a = (a + 0x7fffu + ((a >> 16) & 1u)) >> 16;
  unsigned int b = __float_as_uint(y);
  b = (b + 0x7fffu + ((b >> 16) & 1u)) & 0xffff0000u;
  return a | b;
}
__device__ __forceinline__ int okf(float v) { return (v == v) && (fabsf(v) < 1e30f); }
__device__ __forceinline__ void nflag(int* diag, int bad, int bit) {
  if (__any(bad)) {
    if ((threadIdx.x & 63) == 0) atomicOr(diag + 2, 1 << bit);
  }
}
__device__ __forceinline__ int clampi(int v, int hi) {
  return (unsigned)v < (unsigned)hi ? v : 0;
}

// ---------------- dtype sniff ----------------

// diag[0]=floats-are-fp32, diag[1]=ints-are-int64, diag[2]=error bitmap
__global__ __launch_bounds__(64) void k_sniff(const void* x, const void* ei, int* diag) {
  int lane = threadIdx.x;
  unsigned int xv = ((const unsigned int*)x)[lane];
  unsigned int e = (xv >> 7) & 0xffu;
  int hit = (e >= 116u && e <= 133u);
  int hits = __popcll(__ballot(hit));
  unsigned int ev = ((const unsigned int*)ei)[2 * lane + 1];
  int nzc = __popcll(__ballot(ev != 0u));
  if (lane == 0) {
    diag[0] = (hits < 32) ? 1 : 0;
    diag[1] = (nzc == 0) ? 1 : 0;
  }
}

// ---------------- build: bucketed scatter, ONE atomic pass ----------------

// rank[i] = atomicAdd(cnt[bucket],1) doubles as the histogram; after a scan,
// in-block position = excl[b] + rank[i]. Coalesced run writes into fixed
// regions [b*CAPF, (b+1)*CAPF) reserved via one global atomic per (block,bucket).
__global__ __launch_bounds__(256) void k_build(const void* ei, const int* __restrict__ diag,
                                               int* __restrict__ cursor, int* __restrict__ ents) {
  __shared__ int spktA[CHUNK];          // 16K  (dst&255)<<17|src
  __shared__ unsigned short sbid[CHUNK];   // 8K   bucket id
  __shared__ unsigned short srank[CHUNK];  // 8K   rank within bucket
  __shared__ int spktB[CHUNK];          // 16K  reordered pkt
  __shared__ int gpos[CHUNK];           // 16K  global dest
  __shared__ int lscan[512];            // 2K   counts -> inclusive scan
  __shared__ int sexcl[NBUK];           // 1.6K
  __shared__ int goff[NBUK];            // 1.6K
  int tid = threadIdx.x, blk = blockIdx.x;
  lscan[tid] = 0; lscan[tid + 256] = 0;
  __syncthreads();
  int i64 = diag[1];
  int base = blk * CHUNK;
  int n = NE - base; n = n > CHUNK ? CHUNK : n;
  for (int i = tid; i < n; i += 256) {
    int sv = clampi(ldi(ei, base + i, i64), NN);
    int dv = clampi(ldi(ei, NE + base + i, i64), NN);
    int b = dv >> 8;
    spktA[i] = ((dv & 255) << 17) | sv;
    sbid[i] = (unsigned short)b;
    srank[i] = (unsigned short)atomicAdd(&lscan[b], 1);
  }
  __syncthreads();
  // inclusive scan of lscan[0..511]
  for (int off = 1; off < 512; off <<= 1) {
    int v0 = (tid >= off) ? lscan[tid - off] : 0;
    int v1 = lscan[tid + 256 - off];
    __syncthreads();
    lscan[tid] += v0;
    lscan[tid + 256] += v1;
    __syncthreads();
  }
  for (int b = tid; b < NBUK; b += 256) {
    int incl = lscan[b];
    int excl = (b > 0) ? lscan[b - 1] : 0;
    int cnt = incl - excl;
    sexcl[b] = excl;
    int rbase = cnt ? atomicAdd(&cursor[b], cnt) : 0;
    goff[b] = b * CAPF + rbase - excl;
  }
  __syncthreads();
  for (int i = tid; i < n; i += 256) {
    int b = sbid[i];
    int rr = sexcl[b] + srank[i];
    spktB[rr] = spktA[i];
    int gp = goff[b] + rr;
    int hi = b * CAPF + CAPF - 1;
    gpos[rr] = gp <= hi ? gp : hi;  // overflow clamp (flagged in k_bsort)
  }
  __syncthreads();
  for (int r = tid; r < n; r += 256) ents[gpos[r]] = spktB[r];
}

// per-bucket counting sort (in-place), ONE atomic pass; emits rowstart/rowend/dinv.
__global__ __launch_bounds__(256) void k_bsort(int* __restrict__ ents, const int* __restrict__ cursor,
                                               int* __restrict__ rowstart, int* __restrict__ rowend,
                                               float* __restrict__ dinv, int* __restrict__ diag) {
  __shared__ int ent[CAPF];               // 40K
  __shared__ unsigned short rnk[CAPF];    // 20K
  __shared__ int lcnt[BN];                // 1K  counts -> inclusive scan
  __shared__ int sexcl[BN];               // 1K
  int tid = threadIdx.x, b = blockIdx.x;
  int bs = b * CAPF;
  int n = cursor[b];
  if (n > CAPF) { n = CAPF; if (tid == 0) atomicOr(diag + 2, 1 << 9); }
  lcnt[tid] = 0;
  __syncthreads();
  for (int i = tid; i < n; i += 256) {
    int e = ents[bs + i];
    ent[i] = e;
    rnk[i] = (unsigned short)atomicAdd(&lcnt[e >> 17], 1);
  }
  __syncthreads();
  int c = lcnt[tid];
  for (int off = 1; off < 256; off <<= 1) {
    int v = (tid >= off) ? lcnt[tid - off] : 0;
    __syncthreads();
    lcnt[tid] += v;
    __syncthreads();
  }
  int excl = lcnt[tid] - c;
  sexcl[tid] = excl;
  int node = (b << 8) + tid;
  if (node < NN) {
    rowstart[node] = bs + excl;
    rowend[node] = bs + excl + c;
    dinv[node] = rsqrtf((float)(c + 1));
  }
  __syncthreads();
  for (int i = tid; i < n; i += 256) {
    int e = ent[i];
    ents[bs + sexcl[e >> 17] + rnk[i]] = e & 0x1FFFF;
  }
}

// ---------------- input transform: hs0 = dinv * (x @ W0), bf16-packed ----------------

__global__ __launch_bounds__(256) void k_t0(const void* __restrict__ x, const void* __restrict__ W0,
                                            const float* __restrict__ dinv,
                                            int* __restrict__ diag, unsigned int* __restrict__ out) {
  __shared__ float ws[NF * NH];
  __shared__ float xs[16 * 129];
  int tid = threadIdx.x;
  int f32 = diag[0];
  if (!f32) {
    const unsigned short* xu = (const unsigned short*)x;
    const unsigned short* wu = (const unsigned short*)W0;
    int wave = tid >> 6, lane = tid & 63;
    int nfe = lane & 15, quad = lane >> 4;
    short8 bfr[4];
#pragma unroll
    for (int mf = 0; mf < 4; ++mf) {
      short8 t;
#pragma unroll
      for (int j = 0; j < 8; ++j) t[j] = (short)wu[(mf * 32 + quad * 8 + j) * NH + nfe];
      bfr[mf] = t;
    }
    int tile = blockIdx.x * 4 + wave;
    if (tile < NT0) {
      int node0 = tile * 16;
      const short8* xrow = (const short8*)(xu + (node0 + nfe) * NF);  // m = nfe
      float4v c = {0.f, 0.f, 0.f, 0.f};
#pragma unroll
      for (int mf = 0; mf < 4; ++mf) {
        short8 a = xrow[mf * 4 + quad];
        c = __builtin_amdgcn_mfma_f32_16x16x32_bf16(a, bfr[mf], c, 0, 0, 0);
      }
      int bad = 0;
#pragma unroll
      for (int r = 0; r < 4; ++r) {
        int node = node0 + quad * 4 + r;
        float v = c[r] * dinv[node];
        float o = __shfl_xor(v, 1);
        if (!(nfe & 1)) out[node * 8 + (nfe >> 1)] = packbf(v, o);
        bad |= !okf(v);
      }
      nflag(diag, bad, 0);
    }
  } else {
    // generic fallback (fp32 floats): LDS staging, 4 tiles per block
    for (int t = 0; t < 4; ++t) {
      int tile = blockIdx.x * 4 + t;
      if (tile >= NT0) break;
      int node0 = tile * 16;
      __syncthreads();
#pragma unroll
      for (int r = 0; r < 8; ++r) ws[tid + 256 * r] = ldf(W0, tid + 256 * r, 1);
#pragma unroll
      for (int r = 0; r < 8; ++r) {
        int idx = tid + 256 * r;
        int row = idx >> 7, col = idx & 127;
        xs[row * 129 + col] = ldf(x, (node0 + row) * NF + col, 1);
      }
      __syncthreads();
      int nl = tid >> 4, f = tid & 15;
      float acc = 0.f;
#pragma unroll 4
      for (int k = 0; k < NF; ++k) acc += xs[nl * 129 + k] * ws[k * NH + f];
      acc *= dinv[node0 + nl];
      float other = __shfl_xor(acc, 1);
      if ((f & 1) == 0) out[(node0 + nl) * 8 + (f >> 1)] = packbf(acc, other);
      nflag(diag, !okf(acc), 0);
    }
  }
}

// ---------------- fused aggregate + PReLU + next transform ----------------

// 4 threads/node, thread p owns features 4p..4p+3 (one uint2 = 8B gather/edge).
__global__ __launch_bounds__(256) void k_aggT(const uint2* __restrict__ hin,
                                              const int* __restrict__ srcs,
                                              const int* __restrict__ rowstart,
                                              const int* __restrict__ rowend,
                                              const float* __restrict__ dinv,
                                              const void* __restrict__ b, const void* __restrict__ a,
                                              const void* __restrict__ Wn,
                                              int* __restrict__ diag, int bit,
                                              uint2* __restrict__ hout) {
  __shared__ float ws[NH * NH];
  int tid = threadIdx.x;
  int f32 = diag[0];
  ws[tid] = ldf(Wn, tid, f32);
  __syncthreads();
  int gid = blockIdx.x * 256 + tid;  // NN*4 = 400000
  if (gid >= NN * 4) return;
  int node = gid >> 2, p = gid & 3;
  uint2 self = hin[gid];
  float acc0 = bf16lo(self.x), acc1 = bf16hi(self.x);
  float acc2 = bf16lo(self.y), acc3 = bf16hi(self.y);
  int e = rowstart[node], e1 = rowend[node];
  for (; e + 4 <= e1; e += 4) {
    int s0 = srcs[e], s1 = srcs[e + 1], s2 = srcs[e + 2], s3 = srcs[e + 3];
    uint2 v0 = hin[s0 * 4 + p];
    uint2 v1 = hin[s1 * 4 + p];
    uint2 v2 = hin[s2 * 4 + p];
    uint2 v3 = hin[s3 * 4 + p];
    acc0 += bf16lo(v0.x) + bf16lo(v1.x) + bf16lo(v2.x) + bf16lo(v3.x);
    acc1 += bf16hi(v0.x) + bf16hi(v1.x) + bf16hi(v2.x) + bf16hi(v3.x);
    acc2 += bf16lo(v0.y) + bf16lo(v1.y) + bf16lo(v2.y) + bf16lo(v3.y);
    acc3 += bf16hi(v0.y) + bf16hi(v1.y) + bf16hi(v2.y) + bf16hi(v3.y);
  }
  for (; e < e1; ++e) {
    uint2 v = hin[srcs[e] * 4 + p];
    acc0 += bf16lo(v.x);
    acc1 += bf16hi(v.x);
    acc2 += bf16lo(v.y);
    acc3 += bf16hi(v.y);
  }
  float dv = dinv[node];
  float av = ldf(a, 0, f32);
  float p0 = dv * acc0 + ldf(b, 4 * p + 0, f32);
  float p1 = dv * acc1 + ldf(b, 4 * p + 1, f32);
  float p2 = dv * acc2 + ldf(b, 4 * p + 2, f32);
  float p3 = dv * acc3 + ldf(b, 4 * p + 3, f32);
  p0 = p0 > 0.f ? p0 : av * p0;
  p1 = p1 > 0.f ? p1 : av * p1;
  p2 = p2 > 0.f ? p2 : av * p2;
  p3 = p3 > 0.f ? p3 : av * p3;
  float t0 = 0.f, t1 = 0.f, t2 = 0.f, t3 = 0.f;
#pragma unroll
  for (int j = 0; j < 4; ++j) {
    float q0 = __shfl(p0, j, 4);
    float q1 = __shfl(p1, j, 4);
    float q2 = __shfl(p2, j, 4);
    float q3 = __shfl(p3, j, 4);
    const float* w0 = &ws[(4 * j) * NH + 4 * p];
    const float* w1 = &ws[(4 * j + 1) * NH + 4 * p];
    const float* w2 = &ws[(4 * j + 2) * NH + 4 * p];
    const float* w3 = &ws[(4 * j + 3) * NH + 4 * p];
    t0 += q0 * w0[0] + q1 * w1[0] + q2 * w2[0] + q3 * w3[0];
    t1 += q0 * w0[1] + q1 * w1[1] + q2 * w2[1] + q3 * w3[1];
    t2 += q0 * w0[2] + q1 * w1[2] + q2 * w2[2] + q3 * w3[2];
    t3 += q0 * w0[3] + q1 * w1[3] + q2 * w2[3] + q3 * w3[3];
  }
  t0 *= dv; t1 *= dv; t2 *= dv; t3 *= dv;
  uint2 o;
  o.x = packbf(t0, t1);
  o.y = packbf(t2, t3);
  hout[gid] = o;
  nflag(diag, !okf(t0) || !okf(t3), bit);
}

// Last hidden layer: aggregate + PReLU + W3 (16->2), out float2 prescaled by dinv.
__global__ __launch_bounds__(256) void k_aggT3(const uint2* __restrict__ hin,
                                               const int* __restrict__ srcs,
                                               const int* __restrict__ rowstart,
                                               const int* __restrict__ rowend,
                                               const float* __restrict__ dinv,
                                               const void* __restrict__ b, const void* __restrict__ a,
                                               const void* __restrict__ W3,
                                               int* __restrict__ diag, float2* __restrict__ hout) {
  __shared__ float ws[NH * NO];
  int tid = threadIdx.x;
  int f32 = diag[0];
  if (tid < NH * NO) ws[tid] = ldf(W3, tid, f32);
  __syncthreads();
  int gid = blockIdx.x * 256 + tid;
  if (gid >= NN * 4) return;
  int node = gid >> 2, p = gid & 3;
  uint2 self = hin[gid];
  float acc0 = bf16lo(self.x), acc1 = bf16hi(self.x);
  float acc2 = bf16lo(self.y), acc3 = bf16hi(self.y);
  int e = rowstart[node], e1 = rowend[node];
  for (; e + 4 <= e1; e += 4) {
    int s0 = srcs[e], s1 = srcs[e + 1], s2 = srcs[e + 2], s3 = srcs[e + 3];
    uint2 v0 = hin[s0 * 4 + p];
    uint2 v1 = hin[s1 * 4 + p];
    uint2 v2 = hin[s2 * 4 + p];
    uint2 v3 = hin[s3 * 4 + p];
    acc0 += bf16lo(v0.x) + bf16lo(v1.x) + bf16lo(v2.x) + bf16lo(v3.x);
    acc1 += bf16hi(v0.x) + bf16hi(v1.x) + bf16hi(v2.x) + bf16hi(v3.x);
    acc2 += bf16lo(v0.y) + bf16lo(v1.y) + bf16lo(v2.y) + bf16lo(v3.y);
    acc3 += bf16hi(v0.y) + bf16hi(v1.y) + bf16hi(v2.y) + bf16hi(v3.y);
  }
  for (; e < e1; ++e) {
    uint2 v = hin[srcs[e] * 4 + p];
    acc0 += bf16lo(v.x);
    acc1 += bf16hi(v.x);
    acc2 += bf16lo(v.y);
    acc3 += bf16hi(v.y);
  }
  float dv = dinv[node];
  float av = ldf(a, 0, f32);
  float p0 = dv * acc0 + ldf(b, 4 * p + 0, f32);
  float p1 = dv * acc1 + ldf(b, 4 * p + 1, f32);
  float p2 = dv * acc2 + ldf(b, 4 * p + 2, f32);
  float p3 = dv * acc3 + ldf(b, 4 * p + 3, f32);
  p0 = p0 > 0.f ? p0 : av * p0;
  p1 = p1 > 0.f ? p1 : av * p1;
  p2 = p2 > 0.f ? p2 : av * p2;
  p3 = p3 > 0.f ? p3 : av * p3;
  float u0 = p0 * ws[(4 * p) * NO]     + p1 * ws[(4 * p + 1) * NO] +
             p2 * ws[(4 * p + 2) * NO] + p3 * ws[(4 * p + 3) * NO];
  float u1 = p0 * ws[(4 * p) * NO + 1]     + p1 * ws[(4 * p + 1) * NO + 1] +
             p2 * ws[(4 * p + 2) * NO + 1] + p3 * ws[(4 * p + 3) * NO + 1];
  u0 += __shfl_xor(u0, 1, 4);
  u0 += __shfl_xor(u0, 2, 4);
  u1 += __shfl_xor(u1, 1, 4);
  u1 += __shfl_xor(u1, 2, 4);
  if (p == 0) hout[node] = make_float2(dv * u0, dv * u1);
  nflag(diag, !okf(u0) || !okf(u1), 6);
}

// Final 2-wide aggregation + b3 + fused mean-pool accumulation.
__global__ __launch_bounds__(256) void k_agg2p(const float2* __restrict__ tin,
                                               const int* __restrict__ srcs,
                                               const int* __restrict__ rowstart,
                                               const int* __restrict__ rowend,
                                               const float* __restrict__ dinv,
                                               const void* __restrict__ b3,
                                               const void* __restrict__ batch,
                                               int* __restrict__ diag, float* __restrict__ pool) {
  __shared__ float ssum[NG * NO];
  __shared__ float scnt[NG];
  int tid = threadIdx.x;
  int f32 = diag[0], i64 = diag[1];
  if (tid < NG * NO) ssum[tid] = 0.f;
  if (tid < NG) scnt[tid] = 0.f;
  __syncthreads();
  int node = blockIdx.x * 256 + tid;
  if (node < NN) {
    float2 t = tin[node];
    float a0 = t.x, a1 = t.y;
    int e = rowstart[node], e1 = rowend[node];
    for (; e + 4 <= e1; e += 4) {
      int s0 = srcs[e], s1 = srcs[e + 1], s2 = srcs[e + 2], s3 = srcs[e + 3];
      float2 h0 = tin[s0], h1 = tin[s1], h2 = tin[s2], h3 = tin[s3];
      a0 += h0.x + h1.x + h2.x + h3.x;
      a1 += h0.y + h1.y + h2.y + h3.y;
    }
    for (; e < e1; ++e) {
      float2 hv = tin[srcs[e]];
      a0 += hv.x;
      a1 += hv.y;
    }
    float dv = dinv[node];
    a0 = dv * a0 + ldf(b3, 0, f32);
    a1 = dv * a1 + ldf(b3, 1, f32);
    int g = ldi(batch, node, i64);
    g = (unsigned)g < NG ? g : 0;
    atomicAdd(&ssum[g * 2], a0);
    atomicAdd(&ssum[g * 2 + 1], a1);
    atomicAdd(&scnt[g], 1.f);
    nflag(diag, !okf(a0) || !okf(a1), 7);
  }
  __syncthreads();
  if (tid < NG * NO && ssum[tid] != 0.f) atomicAdd(&pool[tid], ssum[tid]);
  if (tid < NG && scnt[tid] != 0.f) atomicAdd(&pool[NG * NO + tid], scnt[tid]);
}

__global__ __launch_bounds__(128) void k_final(const float* __restrict__ pool,
                                               const int* __restrict__ diag, void* __restrict__ out) {
  int i = threadIdx.x;
  int f32 = diag[0], i64 = diag[1], stg = diag[2];
  float c = pool[NG * NO + (i >> 1)];
  c = c > 1.f ? c : 1.f;
  float v = pool[i] / c;
  if (stg != 0 || !okf(v)) {
    int stage = stg ? __ffs(stg) : 15;
    v = 1024.0f + stage * 64.0f + f32 * 16.0f + i64 * 8.0f;
  }
  stf(out, i, v, f32);
}

__global__ __launch_bounds__(128) void k_diag_ws(void* out, float v) {
  unsigned int w = __float_as_uint(v);
  ((unsigned short*)out)[threadIdx.x] = (unsigned short)(w >> 16);
}

// ---------------- launch ----------------

extern "C" void kernel_launch(void* const* d_in, const int* in_sizes, int n_in,
                              void* d_out, int out_size, void* d_ws, size_t ws_size,
                              hipStream_t stream) {
  const void* x  = d_in[0];
  const void* ei = d_in[1];
  const void* batch = d_in[2];
  const void* W0 = d_in[3];
  const void* b0 = d_in[4];
  const void* a0 = d_in[5];
  const void* W1 = d_in[6];
  const void* b1 = d_in[7];
  const void* a1 = d_in[8];
  const void* W2 = d_in[9];
  const void* b2 = d_in[10];
  const void* a2 = d_in[11];
  const void* W3 = d_in[12];
  const void* b3 = d_in[13];

  // workspace layout (bytes)
  char* w = (char*)d_ws;
  int* diag         = (int*)(w + 0);            // 64
  float* pool       = (float*)(w + 64);         // 768 -> 832, pad 896
  int* cursor       = (int*)(w + 896);          // 391*4=1564 -> 2460, pad 2496
  float* dinv       = (float*)(w + 2496);       // 400000 -> 402496
  int* rowstart     = (int*)(w + 402496);       // 400000 -> 802496
  int* rowend       = (int*)(w + 802496);       // 400000 -> 1202496
  int* ents         = (int*)(w + 1202496);      // 391*10240*4 = 16015360 -> 17217856
  uint2* hsA        = (uint2*)(w + 17217856);   // 3.2MB -> 20417856 (bf16x2 packed)
  uint2* hsB        = (uint2*)(w + 20417856);   // 3.2MB -> 23617856
  float2* hs3       = (float2*)(w + 23617856);  // 800000 -> 24417856
  const size_t NEED = 24417856;

  if (ws_size < NEED) {
    k_diag_ws<<<1, 128, 0, stream>>>(d_out, (float)ws_size);
    return;
  }

  hipMemsetAsync(d_ws, 0, 2496, stream);  // diag + pool + cursor

  k_sniff<<<1, 64, 0, stream>>>(x, ei, diag);

  // build (single-atomic-pass bucket scatter + per-bucket compaction sort)
  k_build<<<NBLKA, 256, 0, stream>>>(ei, diag, cursor, ents);
  k_bsort<<<NBUK, 256, 0, stream>>>(ents, cursor, rowstart, rowend, dinv, diag);

  // layers (fused agg + transform; h bf16-packed, L2-resident)
  k_t0<<<(NT0 + 3) / 4, 256, 0, stream>>>(x, W0, dinv, diag, (unsigned int*)hsA);
  k_aggT<<<(NN * 4 + 255) / 256, 256, 0, stream>>>(hsA, ents, rowstart, rowend, dinv, b0, a0, W1, diag, 1, hsB);
  k_aggT<<<(NN * 4 + 255) / 256, 256, 0, stream>>>(hsB, ents, rowstart, rowend, dinv, b1, a1, W2, diag, 3, hsA);
  k_aggT3<<<(NN * 4 + 255) / 256, 256, 0, stream>>>(hsA, ents, rowstart, rowend, dinv, b2, a2, W3, diag, hs3);
  k_agg2p<<<NBLK, 256, 0, stream>>>(hs3, ents, rowstart, rowend, dinv, b3, batch, diag, pool);

  k_final<<<1, 128, 0, stream>>>(pool, diag, d_out);
}

// Round 10
// 302.229 us; speedup vs baseline: 1.0707x; 1.0707x over previous
//
#include <hip/hip_runtime.h>

// GCN: 100K nodes, 3.2M edges, 128 -> 16 -> 16 -> 16 -> 2, mean-pool to 64 graphs.
// R10 vs R9 (k_build was latency-bound at 8-waves/CU occupancy, NOT atomic-bound):
//  (1) k_build / k_bsort: 512 threads/block (2 blocks/CU -> 16 waves/CU).
//  (2) agg kernels: x8 unroll (8 independent gathers in flight).
//  (3) memset folded into k_sniff (zeroing done on-device).
// h stored bf16-packed (L2-resident); MFMA k_t0; dtype-adaptive IO.

#define NN 100000
#define NE 3200000
#define NF 128
#define NH 16
#define NO 2
#define NG 64
#define NBLK 391        // ceil(NN/256)
#define BN 256          // nodes per bucket
#define NBUK 391        // ceil(NN/BN)
#define CHUNK 4096
#define NBLKA 782       // ceil(NE/CHUNK)
#define CAPF 10240      // bucket region capacity (mean 8184, sigma ~90)
#define NT0 6250        // 16-node tiles

typedef __attribute__((ext_vector_type(8))) short short8;
typedef __attribute__((ext_vector_type(4))) float float4v;

// ---------------- dtype-dispatched IO helpers ----------------

__device__ __forceinline__ float ldf(const void* p, int i, int f32) {
  if (f32) return ((const float*)p)[i];
  unsigned int u = ((const unsigned short*)p)[i];
  return __uint_as_float(u << 16);
}
__device__ __forceinline__ int ldi(const void* p, int i, int i64) {
  if (i64) return (int)((const long long*)p)[i];
  return ((const int*)p)[i];
}
__device__ __forceinline__ void stf(void* p, int i, float v, int f32) {
  if (f32) {
    ((float*)p)[i] = v;
  } else {
    unsigned int w = __float_as_uint(v);
    unsigned int r = (w + 0x7fffu + ((w >> 16) & 1u)) >> 16;
    ((unsigned short*)p)[i] = (unsigned short)r;
  }
}
__device__ __forceinline__ float bf16lo(unsigned int u) { return __uint_as_float(u << 16); }
__device__ __forceinline__ float bf16hi(unsigned int u) { return __uint_as_float(u & 0xffff0000u); }
__device__ __forceinline__ unsigned int packbf(float x, float y) {
  unsigned int a = __float_as_uint(x);
  a = (a + 0x7fffu + ((a >> 16) & 1u)) >> 16;
  unsigned int b = __float_as_uint(y);
  b = (b + 0x7fffu + ((b >> 16) & 1u)) & 0xffff0000u;
  return a | b;
}
__device__ __forceinline__ int okf(float v) { return (v == v) && (fabsf(v) < 1e30f); }
__device__ __forceinline__ void nflag(int* diag, int bad, int bit) {
  if (__any(bad)) {
    if ((threadIdx.x & 63) == 0) atomicOr(diag + 2, 1 << bit);
  }
}
__device__ __forceinline__ int clampi(int v, int hi) {
  return (unsigned)v < (unsigned)hi ? v : 0;
}

// ---------------- dtype sniff + workspace-control zeroing ----------------

// zbase = first 2496 B of ws: diag(16 ints) | pool(192 fl) | cursor(391+ ints)
__global__ __launch_bounds__(1024) void k_sniff(const void* x, const void* ei, int* zbase) {
  int tid = threadIdx.x;
  if (tid < 624) zbase[tid] = 0;
  __syncthreads();
  if (tid < 64) {
    unsigned int xv = ((const unsigned int*)x)[tid];
    unsigned int e = (xv >> 7) & 0xffu;
    int hit = (e >= 116u && e <= 133u);
    int hits = __popcll(__ballot(hit));
    unsigned int ev = ((const unsigned int*)ei)[2 * tid + 1];
    int nzc = __popcll(__ballot(ev != 0u));
    if (tid == 0) {
      zbase[0] = (hits < 32) ? 1 : 0;  // floats are fp32
      zbase[1] = (nzc == 0) ? 1 : 0;   // ints are int64
    }
  }
}

// ---------------- build: bucketed scatter, one LDS-atomic pass, 512 threads ----------------

__global__ __launch_bounds__(512) void k_build(const void* ei, const int* __restrict__ diag,
                                               int* __restrict__ cursor, int* __restrict__ ents) {
  __shared__ int spktA[CHUNK];             // 16K  (dst&255)<<17|src
  __shared__ unsigned short sbid[CHUNK];   // 8K   bucket id
  __shared__ unsigned short srank[CHUNK];  // 8K   rank within bucket
  __shared__ int spktB[CHUNK];             // 16K  reordered pkt
  __shared__ int gpos[CHUNK];              // 16K  global dest
  __shared__ int lscan[512];               // 2K   counts -> inclusive scan
  __shared__ int sexcl[NBUK];              // 1.6K
  __shared__ int goff[NBUK];               // 1.6K
  int tid = threadIdx.x, blk = blockIdx.x;
  lscan[tid] = 0;
  __syncthreads();
  int i64 = diag[1];
  int base = blk * CHUNK;
  int n = NE - base; n = n > CHUNK ? CHUNK : n;
  for (int i = tid; i < n; i += 512) {
    int sv = clampi(ldi(ei, base + i, i64), NN);
    int dv = clampi(ldi(ei, NE + base + i, i64), NN);
    int b = dv >> 8;
    spktA[i] = ((dv & 255) << 17) | sv;
    sbid[i] = (unsigned short)b;
    srank[i] = (unsigned short)atomicAdd(&lscan[b], 1);
  }
  __syncthreads();
  // inclusive scan of lscan[0..511], 512 threads
  for (int off = 1; off < 512; off <<= 1) {
    int v = (tid >= off) ? lscan[tid - off] : 0;
    __syncthreads();
    lscan[tid] += v;
    __syncthreads();
  }
  if (tid < NBUK) {
    int b = tid;
    int incl = lscan[b];
    int excl = (b > 0) ? lscan[b - 1] : 0;
    int cnt = incl - excl;
    sexcl[b] = excl;
    int rbase = cnt ? atomicAdd(&cursor[b], cnt) : 0;
    goff[b] = b * CAPF + rbase - excl;
  }
  __syncthreads();
  for (int i = tid; i < n; i += 512) {
    int b = sbid[i];
    int rr = sexcl[b] + srank[i];
    spktB[rr] = spktA[i];
    int gp = goff[b] + rr;
    int hi = b * CAPF + CAPF - 1;
    gpos[rr] = gp <= hi ? gp : hi;  // overflow clamp (flagged in k_bsort)
  }
  __syncthreads();
  for (int r = tid; r < n; r += 512) ents[gpos[r]] = spktB[r];
}

// per-bucket counting sort (in-place), one atomic pass, 512 threads.
__global__ __launch_bounds__(512) void k_bsort(int* __restrict__ ents, const int* __restrict__ cursor,
                                               int* __restrict__ rowstart, int* __restrict__ rowend,
                                               float* __restrict__ dinv, int* __restrict__ diag) {
  __shared__ int ent[CAPF];               // 40K
  __shared__ unsigned short rnk[CAPF];    // 20K
  __shared__ int lcnt[BN];                // 1K  counts -> inclusive scan
  __shared__ int sexcl[BN];               // 1K
  int tid = threadIdx.x, b = blockIdx.x;
  int bs = b * CAPF;
  int n = cursor[b];
  if (n > CAPF) { n = CAPF; if (tid == 0) atomicOr(diag + 2, 1 << 9); }
  if (tid < BN) lcnt[tid] = 0;
  __syncthreads();
  for (int i = tid; i < n; i += 512) {
    int e = ents[bs + i];
    ent[i] = e;
    rnk[i] = (unsigned short)atomicAdd(&lcnt[e >> 17], 1);
  }
  __syncthreads();
  int c = (tid < BN) ? lcnt[tid] : 0;
  for (int off = 1; off < BN; off <<= 1) {
    int v = (tid < BN && tid >= off) ? lcnt[tid - off] : 0;
    __syncthreads();
    if (tid < BN) lcnt[tid] += v;
    __syncthreads();
  }
  if (tid < BN) {
    int excl = lcnt[tid] - c;
    sexcl[tid] = excl;
    int node = (b << 8) + tid;
    if (node < NN) {
      rowstart[node] = bs + excl;
      rowend[node] = bs + excl + c;
      dinv[node] = rsqrtf((float)(c + 1));
    }
  }
  __syncthreads();
  for (int i = tid; i < n; i += 512) {
    int e = ent[i];
    ents[bs + sexcl[e >> 17] + rnk[i]] = e & 0x1FFFF;
  }
}

// ---------------- input transform: hs0 = dinv * (x @ W0), bf16-packed ----------------

__global__ __launch_bounds__(256) void k_t0(const void* __restrict__ x, const void* __restrict__ W0,
                                            const float* __restrict__ dinv,
                                            int* __restrict__ diag, unsigned int* __restrict__ out) {
  __shared__ float ws[NF * NH];
  __shared__ float xs[16 * 129];
  int tid = threadIdx.x;
  int f32 = diag[0];
  if (!f32) {
    const unsigned short* xu = (const unsigned short*)x;
    const unsigned short* wu = (const unsigned short*)W0;
    int wave = tid >> 6, lane = tid & 63;
    int nfe = lane & 15, quad = lane >> 4;
    short8 bfr[4];
#pragma unroll
    for (int mf = 0; mf < 4; ++mf) {
      short8 t;
#pragma unroll
      for (int j = 0; j < 8; ++j) t[j] = (short)wu[(mf * 32 + quad * 8 + j) * NH + nfe];
      bfr[mf] = t;
    }
    int tile = blockIdx.x * 4 + wave;
    if (tile < NT0) {
      int node0 = tile * 16;
      const short8* xrow = (const short8*)(xu + (node0 + nfe) * NF);  // m = nfe
      float4v c = {0.f, 0.f, 0.f, 0.f};
#pragma unroll
      for (int mf = 0; mf < 4; ++mf) {
        short8 a = xrow[mf * 4 + quad];
        c = __builtin_amdgcn_mfma_f32_16x16x32_bf16(a, bfr[mf], c, 0, 0, 0);
      }
      int bad = 0;
#pragma unroll
      for (int r = 0; r < 4; ++r) {
        int node = node0 + quad * 4 + r;
        float v = c[r] * dinv[node];
        float o = __shfl_xor(v, 1);
        if (!(nfe & 1)) out[node * 8 + (nfe >> 1)] = packbf(v, o);
        bad |= !okf(v);
      }
      nflag(diag, bad, 0);
    }
  } else {
    // generic fallback (fp32 floats): LDS staging, 4 tiles per block
    for (int t = 0; t < 4; ++t) {
      int tile = blockIdx.x * 4 + t;
      if (tile >= NT0) break;
      int node0 = tile * 16;
      __syncthreads();
#pragma unroll
      for (int r = 0; r < 8; ++r) ws[tid + 256 * r] = ldf(W0, tid + 256 * r, 1);
#pragma unroll
      for (int r = 0; r < 8; ++r) {
        int idx = tid + 256 * r;
        int row = idx >> 7, col = idx & 127;
        xs[row * 129 + col] = ldf(x, (node0 + row) * NF + col, 1);
      }
      __syncthreads();
      int nl = tid >> 4, f = tid & 15;
      float acc = 0.f;
#pragma unroll 4
      for (int k = 0; k < NF; ++k) acc += xs[nl * 129 + k] * ws[k * NH + f];
      acc *= dinv[node0 + nl];
      float other = __shfl_xor(acc, 1);
      if ((f & 1) == 0) out[(node0 + nl) * 8 + (f >> 1)] = packbf(acc, other);
      nflag(diag, !okf(acc), 0);
    }
  }
}

// ---------------- fused aggregate + PReLU + next transform ----------------

// 4 threads/node, thread p owns features 4p..4p+3 (one uint2 = 8B gather/edge).
// Edge loop x8-unrolled: 8 independent gathers in flight per lane.
__global__ __launch_bounds__(256) void k_aggT(const uint2* __restrict__ hin,
                                              const int* __restrict__ srcs,
                                              const int* __restrict__ rowstart,
                                              const int* __restrict__ rowend,
                                              const float* __restrict__ dinv,
                                              const void* __restrict__ b, const void* __restrict__ a,
                                              const void* __restrict__ Wn,
                                              int* __restrict__ diag, int bit,
                                              uint2* __restrict__ hout) {
  __shared__ float ws[NH * NH];
  int tid = threadIdx.x;
  int f32 = diag[0];
  ws[tid] = ldf(Wn, tid, f32);
  __syncthreads();
  int gid = blockIdx.x * 256 + tid;  // NN*4 = 400000
  if (gid >= NN * 4) return;
  int node = gid >> 2, p = gid & 3;
  uint2 self = hin[gid];
  float acc0 = bf16lo(self.x), acc1 = bf16hi(self.x);
  float acc2 = bf16lo(self.y), acc3 = bf16hi(self.y);
  int e = rowstart[node], e1 = rowend[node];
  for (; e + 8 <= e1; e += 8) {
    uint2 v[8];
#pragma unroll
    for (int k = 0; k < 8; ++k) v[k] = hin[srcs[e + k] * 4 + p];
#pragma unroll
    for (int k = 0; k < 8; ++k) {
      acc0 += bf16lo(v[k].x);
      acc1 += bf16hi(v[k].x);
      acc2 += bf16lo(v[k].y);
      acc3 += bf16hi(v[k].y);
    }
  }
  for (; e + 2 <= e1; e += 2) {
    uint2 va = hin[srcs[e] * 4 + p];
    uint2 vb = hin[srcs[e + 1] * 4 + p];
    acc0 += bf16lo(va.x) + bf16lo(vb.x);
    acc1 += bf16hi(va.x) + bf16hi(vb.x);
    acc2 += bf16lo(va.y) + bf16lo(vb.y);
    acc3 += bf16hi(va.y) + bf16hi(vb.y);
  }
  if (e < e1) {
    uint2 v = hin[srcs[e] * 4 + p];
    acc0 += bf16lo(v.x);
    acc1 += bf16hi(v.x);
    acc2 += bf16lo(v.y);
    acc3 += bf16hi(v.y);
  }
  float dv = dinv[node];
  float av = ldf(a, 0, f32);
  float p0 = dv * acc0 + ldf(b, 4 * p + 0, f32);
  float p1 = dv * acc1 + ldf(b, 4 * p + 1, f32);
  float p2 = dv * acc2 + ldf(b, 4 * p + 2, f32);
  float p3 = dv * acc3 + ldf(b, 4 * p + 3, f32);
  p0 = p0 > 0.f ? p0 : av * p0;
  p1 = p1 > 0.f ? p1 : av * p1;
  p2 = p2 > 0.f ? p2 : av * p2;
  p3 = p3 > 0.f ? p3 : av * p3;
  float t0 = 0.f, t1 = 0.f, t2 = 0.f, t3 = 0.f;
#pragma unroll
  for (int j = 0; j < 4; ++j) {
    float q0 = __shfl(p0, j, 4);
    float q1 = __shfl(p1, j, 4);
    float q2 = __shfl(p2, j, 4);
    float q3 = __shfl(p3, j, 4);
    const float* w0 = &ws[(4 * j) * NH + 4 * p];
    const float* w1 = &ws[(4 * j + 1) * NH + 4 * p];
    const float* w2 = &ws[(4 * j + 2) * NH + 4 * p];
    const float* w3 = &ws[(4 * j + 3) * NH + 4 * p];
    t0 += q0 * w0[0] + q1 * w1[0] + q2 * w2[0] + q3 * w3[0];
    t1 += q0 * w0[1] + q1 * w1[1] + q2 * w2[1] + q3 * w3[1];
    t2 += q0 * w0[2] + q1 * w1[2] + q2 * w2[2] + q3 * w3[2];
    t3 += q0 * w0[3] + q1 * w1[3] + q2 * w2[3] + q3 * w3[3];
  }
  t0 *= dv; t1 *= dv; t2 *= dv; t3 *= dv;
  uint2 o;
  o.x = packbf(t0, t1);
  o.y = packbf(t2, t3);
  hout[gid] = o;
  nflag(diag, !okf(t0) || !okf(t3), bit);
}

// Last hidden layer: aggregate + PReLU + W3 (16->2), out float2 prescaled by dinv.
__global__ __launch_bounds__(256) void k_aggT3(const uint2* __restrict__ hin,
                                               const int* __restrict__ srcs,
                                               const int* __restrict__ rowstart,
                                               const int* __restrict__ rowend,
                                               const float* __restrict__ dinv,
                                               const void* __restrict__ b, const void* __restrict__ a,
                                               const void* __restrict__ W3,
                                               int* __restrict__ diag, float2* __restrict__ hout) {
  __shared__ float ws[NH * NO];
  int tid = threadIdx.x;
  int f32 = diag[0];
  if (tid < NH * NO) ws[tid] = ldf(W3, tid, f32);
  __syncthreads();
  int gid = blockIdx.x * 256 + tid;
  if (gid >= NN * 4) return;
  int node = gid >> 2, p = gid & 3;
  uint2 self = hin[gid];
  float acc0 = bf16lo(self.x), acc1 = bf16hi(self.x);
  float acc2 = bf16lo(self.y), acc3 = bf16hi(self.y);
  int e = rowstart[node], e1 = rowend[node];
  for (; e + 8 <= e1; e += 8) {
    uint2 v[8];
#pragma unroll
    for (int k = 0; k < 8; ++k) v[k] = hin[srcs[e + k] * 4 + p];
#pragma unroll
    for (int k = 0; k < 8; ++k) {
      acc0 += bf16lo(v[k].x);
      acc1 += bf16hi(v[k].x);
      acc2 += bf16lo(v[k].y);
      acc3 += bf16hi(v[k].y);
    }
  }
  for (; e + 2 <= e1; e += 2) {
    uint2 va = hin[srcs[e] * 4 + p];
    uint2 vb = hin[srcs[e + 1] * 4 + p];
    acc0 += bf16lo(va.x) + bf16lo(vb.x);
    acc1 += bf16hi(va.x) + bf16hi(vb.x);
    acc2 += bf16lo(va.y) + bf16lo(vb.y);
    acc3 += bf16hi(va.y) + bf16hi(vb.y);
  }
  if (e < e1) {
    uint2 v = hin[srcs[e] * 4 + p];
    acc0 += bf16lo(v.x);
    acc1 += bf16hi(v.x);
    acc2 += bf16lo(v.y);
    acc3 += bf16hi(v.y);
  }
  float dv = dinv[node];
  float av = ldf(a, 0, f32);
  float p0 = dv * acc0 + ldf(b, 4 * p + 0, f32);
  float p1 = dv * acc1 + ldf(b, 4 * p + 1, f32);
  float p2 = dv * acc2 + ldf(b, 4 * p + 2, f32);
  float p3 = dv * acc3 + ldf(b, 4 * p + 3, f32);
  p0 = p0 > 0.f ? p0 : av * p0;
  p1 = p1 > 0.f ? p1 : av * p1;
  p2 = p2 > 0.f ? p2 : av * p2;
  p3 = p3 > 0.f ? p3 : av * p3;
  float u0 = p0 * ws[(4 * p) * NO]     + p1 * ws[(4 * p + 1) * NO] +
             p2 * ws[(4 * p + 2) * NO] + p3 * ws[(4 * p + 3) * NO];
  float u1 = p0 * ws[(4 * p) * NO + 1]     + p1 * ws[(4 * p + 1) * NO + 1] +
             p2 * ws[(4 * p + 2) * NO + 1] + p3 * ws[(4 * p + 3) * NO + 1];
  u0 += __shfl_xor(u0, 1, 4);
  u0 += __shfl_xor(u0, 2, 4);
  u1 += __shfl_xor(u1, 1, 4);
  u1 += __shfl_xor(u1, 2, 4);
  if (p == 0) hout[node] = make_float2(dv * u0, dv * u1);
  nflag(diag, !okf(u0) || !okf(u1), 6);
}

// Final 2-wide aggregation + b3 + fused mean-pool accumulation.
__global__ __launch_bounds__(256) void k_agg2p(const float2* __restrict__ tin,
                                               const int* __restrict__ srcs,
                                               const int* __restrict__ rowstart,
                                               const int* __restrict__ rowend,
                                               const float* __restrict__ dinv,
                                               const void* __restrict__ b3,
                                               const void* __restrict__ batch,
                                               int* __restrict__ diag, float* __restrict__ pool) {
  __shared__ float ssum[NG * NO];
  __shared__ float scnt[NG];
  int tid = threadIdx.x;
  int f32 = diag[0], i64 = diag[1];
  if (tid < NG * NO) ssum[tid] = 0.f;
  if (tid < NG) scnt[tid] = 0.f;
  __syncthreads();
  int node = blockIdx.x * 256 + tid;
  if (node < NN) {
    float2 t = tin[node];
    float a0 = t.x, a1 = t.y;
    int e = rowstart[node], e1 = rowend[node];
    for (; e + 4 <= e1; e += 4) {
      int s0 = srcs[e], s1 = srcs[e + 1], s2 = srcs[e + 2], s3 = srcs[e + 3];
      float2 h0 = tin[s0], h1 = tin[s1], h2 = tin[s2], h3 = tin[s3];
      a0 += h0.x + h1.x + h2.x + h3.x;
      a1 += h0.y + h1.y + h2.y + h3.y;
    }
    for (; e < e1; ++e) {
      float2 hv = tin[srcs[e]];
      a0 += hv.x;
      a1 += hv.y;
    }
    float dv = dinv[node];
    a0 = dv * a0 + ldf(b3, 0, f32);
    a1 = dv * a1 + ldf(b3, 1, f32);
    int g = ldi(batch, node, i64);
    g = (unsigned)g < NG ? g : 0;
    atomicAdd(&ssum[g * 2], a0);
    atomicAdd(&ssum[g * 2 + 1], a1);
    atomicAdd(&scnt[g], 1.f);
    nflag(diag, !okf(a0) || !okf(a1), 7);
  }
  __syncthreads();
  if (tid < NG * NO && ssum[tid] != 0.f) atomicAdd(&pool[tid], ssum[tid]);
  if (tid < NG && scnt[tid] != 0.f) atomicAdd(&pool[NG * NO + tid], scnt[tid]);
}

__global__ __launch_bounds__(128) void k_final(const float* __restrict__ pool,
                                               const int* __restrict__ diag, void* __restrict__ out) {
  int i = threadIdx.x;
  int f32 = diag[0], i64 = diag[1], stg = diag[2];
  float c = pool[NG * NO + (i >> 1)];
  c = c > 1.f ? c : 1.f;
  float v = pool[i] / c;
  if (stg != 0 || !okf(v)) {
    int stage = stg ? __ffs(stg) : 15;
    v = 1024.0f + stage * 64.0f + f32 * 16.0f + i64 * 8.0f;
  }
  stf(out, i, v, f32);
}

__global__ __launch_bounds__(128) void k_diag_ws(void* out, float v) {
  unsigned int w = __float_as_uint(v);
  ((unsigned short*)out)[threadIdx.x] = (unsigned short)(w >> 16);
}

// ---------------- launch ----------------

extern "C" void kernel_launch(void* const* d_in, const int* in_sizes, int n_in,
                              void* d_out, int out_size, void* d_ws, size_t ws_size,
                              hipStream_t stream) {
  const void* x  = d_in[0];
  const void* ei = d_in[1];
  const void* batch = d_in[2];
  const void* W0 = d_in[3];
  const void* b0 = d_in[4];
  const void* a0 = d_in[5];
  const void* W1 = d_in[6];
  const void* b1 = d_in[7];
  const void* a1 = d_in[8];
  const void* W2 = d_in[9];
  const void* b2 = d_in[10];
  const void* a2 = d_in[11];
  const void* W3 = d_in[12];
  const void* b3 = d_in[13];

  // workspace layout (bytes)
  char* w = (char*)d_ws;
  int* diag         = (int*)(w + 0);            // 64
  float* pool       = (float*)(w + 64);         // 768 -> 832, pad 896
  int* cursor       = (int*)(w + 896);          // 391*4=1564 -> 2460, pad 2496
  float* dinv       = (float*)(w + 2496);       // 400000 -> 402496
  int* rowstart     = (int*)(w + 402496);       // 400000 -> 802496
  int* rowend       = (int*)(w + 802496);       // 400000 -> 1202496
  int* ents         = (int*)(w + 1202496);      // 391*10240*4 = 16015360 -> 17217856
  uint2* hsA        = (uint2*)(w + 17217856);   // 3.2MB -> 20417856 (bf16x2 packed)
  uint2* hsB        = (uint2*)(w + 20417856);   // 3.2MB -> 23617856
  float2* hs3       = (float2*)(w + 23617856);  // 800000 -> 24417856
  const size_t NEED = 24417856;

  if (ws_size < NEED) {
    k_diag_ws<<<1, 128, 0, stream>>>(d_out, (float)ws_size);
    return;
  }

  // sniff + zero diag/pool/cursor in one dispatch
  k_sniff<<<1, 1024, 0, stream>>>(x, ei, (int*)w);

  // build (bucket scatter + per-bucket compaction sort), 512-thread blocks
  k_build<<<NBLKA, 512, 0, stream>>>(ei, diag, cursor, ents);
  k_bsort<<<NBUK, 512, 0, stream>>>(ents, cursor, rowstart, rowend, dinv, diag);

  // layers (fused agg + transform; h bf16-packed, L2-resident)
  k_t0<<<(NT0 + 3) / 4, 256, 0, stream>>>(x, W0, dinv, diag, (unsigned int*)hsA);
  k_aggT<<<(NN * 4 + 255) / 256, 256, 0, stream>>>(hsA, ents, rowstart, rowend, dinv, b0, a0, W1, diag, 1, hsB);
  k_aggT<<<(NN * 4 + 255) / 256, 256, 0, stream>>>(hsB, ents, rowstart, rowend, dinv, b1, a1, W2, diag, 3, hsA);
  k_aggT3<<<(NN * 4 + 255) / 256, 256, 0, stream>>>(hsA, ents, rowstart, rowend, dinv, b2, a2, W3, diag, hs3);
  k_agg2p<<<NBLK, 256, 0, stream>>>(hs3, ents, rowstart, rowend, dinv, b3, batch, diag, pool);

  k_final<<<1, 128, 0, stream>>>(pool, diag, d_out);
}